// Round 3
// baseline (627.130 us; speedup 1.0000x reference)
//
#include <hip/hip_runtime.h>
#include <hip/hip_bf16.h>

#define N_NODES 50000
#define N_EDGES 800000
#define IN_CH 256
#define HEADS 8
#define OUT_CH 32
#define HC 256            // HEADS*OUT_CH
#define E_TOT (N_EDGES + N_NODES)
#define NEG_SLOPE 0.2f

// ---- bf16 helpers via raw bits (RNE), no hip_bf16 API dependence ----
__device__ __forceinline__ unsigned short f2bf(float f) {
    unsigned int u = __float_as_uint(f);
    unsigned int r = (u + 0x7FFFu + ((u >> 16) & 1u)) >> 16;
    return (unsigned short)r;
}
__device__ __forceinline__ float bf2f(unsigned short b) {
    return __uint_as_float(((unsigned int)b) << 16);
}

// ---------------- GEMM: Wh(bf16) = x @ W^T, fused el/er epilogue ----------------
// M=50000, N=256, K=256. Block: 64 rows x 64 cols, 256 threads, 4x4 acc/thread.
__global__ __launch_bounds__(256) void gemm_kernel(const float* __restrict__ x,
                                                   const float* __restrict__ W,
                                                   const float* __restrict__ a_left,
                                                   const float* __restrict__ a_right,
                                                   unsigned short* __restrict__ Wh,
                                                   float* __restrict__ el,
                                                   float* __restrict__ er) {
    __shared__ float As[32][64];
    __shared__ float Bs[32][64];
    const int m0 = blockIdx.x * 64;
    const int n0 = blockIdx.y * 64;
    const int t  = threadIdx.x;
    const int ty = t >> 4;      // 0..15
    const int tx = t & 15;      // 0..15
    float acc[4][4] = {};

    for (int k0 = 0; k0 < IN_CH; k0 += 32) {
#pragma unroll
        for (int it = 0; it < 2; ++it) {
            int i  = t + it * 256;
            int r  = i >> 3;
            int kq = (i & 7) << 2;
            int row = m0 + r;
            float4 v = make_float4(0.f, 0.f, 0.f, 0.f);
            if (row < N_NODES) v = *(const float4*)&x[(size_t)row * IN_CH + k0 + kq];
            As[kq + 0][r] = v.x; As[kq + 1][r] = v.y; As[kq + 2][r] = v.z; As[kq + 3][r] = v.w;
            float4 w = *(const float4*)&W[(size_t)(n0 + r) * IN_CH + k0 + kq];
            Bs[kq + 0][r] = w.x; Bs[kq + 1][r] = w.y; Bs[kq + 2][r] = w.z; Bs[kq + 3][r] = w.w;
        }
        __syncthreads();
#pragma unroll
        for (int k = 0; k < 32; ++k) {
            float4 a4 = *(const float4*)&As[k][ty * 4];
            float4 b4 = *(const float4*)&Bs[k][tx * 4];
            float a[4] = {a4.x, a4.y, a4.z, a4.w};
            float b[4] = {b4.x, b4.y, b4.z, b4.w};
#pragma unroll
            for (int i = 0; i < 4; ++i)
#pragma unroll
                for (int j = 0; j < 4; ++j)
                    acc[i][j] = fmaf(a[i], b[j], acc[i][j]);
        }
        __syncthreads();
    }

    // Epilogue: this thread's 4 cols (n0 + tx*4 .. +3) all lie in one head.
    const int h  = (n0 >> 5) + (tx >> 3);       // global head 0..7
    const int c0 = (tx * 4) & 31;               // channel within head
    float4 al = *(const float4*)&a_left [h * OUT_CH + c0];
    float4 ar = *(const float4*)&a_right[h * OUT_CH + c0];
#pragma unroll
    for (int i = 0; i < 4; ++i) {
        int row = m0 + ty * 4 + i;
        float pl = acc[i][0] * al.x + acc[i][1] * al.y + acc[i][2] * al.z + acc[i][3] * al.w;
        float pr = acc[i][0] * ar.x + acc[i][1] * ar.y + acc[i][2] * ar.z + acc[i][3] * ar.w;
#pragma unroll
        for (int m = 1; m < 8; m <<= 1) {       // reduce over the 8 threads (32 cols) of this head
            pl += __shfl_xor(pl, m, 8);
            pr += __shfl_xor(pr, m, 8);
        }
        if (row < N_NODES) {
            if ((tx & 7) == 0) {                // exactly one writer per (row, head)
                el[row * HEADS + h] = pl;
                er[row * HEADS + h] = pr;
            }
            ushort4 o;
            o.x = f2bf(acc[i][0]); o.y = f2bf(acc[i][1]);
            o.z = f2bf(acc[i][2]); o.w = f2bf(acc[i][3]);
            *(ushort4*)&Wh[(size_t)row * HC + n0 + tx * 4] = o;
        }
    }
}

// ---------------- CSR build ----------------
__global__ void zero_kernel(int* __restrict__ p, int n) {
    int i = blockIdx.x * blockDim.x + threadIdx.x;
    if (i < n) p[i] = 0;
}

__global__ void hist_kernel(const int* __restrict__ src, const int* __restrict__ dst,
                            int* __restrict__ count) {
    int e = blockIdx.x * blockDim.x + threadIdx.x;
    if (e >= E_TOT) return;
    int s, d;
    if (e < N_EDGES) { s = src[e]; d = dst[e]; } else { s = d = e - N_EDGES; }
    if ((unsigned)s >= N_NODES || (unsigned)d >= N_NODES) return;  // fault-proofing
    atomicAdd(&count[d], 1);
}

__global__ __launch_bounds__(256) void scan_kernel(const int* __restrict__ count,
                                                   int* __restrict__ offset,
                                                   int* __restrict__ cursor) {
    __shared__ int wtot[4];
    __shared__ int wbase[4];
    __shared__ int running_s;
    int t = threadIdx.x, lane = t & 63, wid = t >> 6;
    if (t == 0) running_s = 0;
    __syncthreads();
    for (int base = 0; base < N_NODES; base += 256) {
        int idx = base + t;
        int v = (idx < N_NODES) ? count[idx] : 0;
        int s = v;
#pragma unroll
        for (int off = 1; off < 64; off <<= 1) {
            int u = __shfl_up(s, off, 64);
            if (lane >= off) s += u;
        }
        if (lane == 63) wtot[wid] = s;
        __syncthreads();
        if (t == 0) {
            int b = running_s;
            for (int w = 0; w < 4; ++w) { wbase[w] = b; b += wtot[w]; }
            running_s = b;
        }
        __syncthreads();
        int excl = s - v + wbase[wid];
        if (idx < N_NODES) { offset[idx] = excl; cursor[idx] = excl; }
        __syncthreads();
    }
    if (t == 0) offset[N_NODES] = running_s;
}

__global__ void scatter_kernel(const int* __restrict__ src, const int* __restrict__ dst,
                               int* __restrict__ cursor, int* __restrict__ srcs) {
    int e = blockIdx.x * blockDim.x + threadIdx.x;
    if (e >= E_TOT) return;
    int s, d;
    if (e < N_EDGES) { s = src[e]; d = dst[e]; } else { s = d = e - N_EDGES; }
    if ((unsigned)s >= N_NODES || (unsigned)d >= N_NODES) return;  // same rule as hist
    int pos = atomicAdd(&cursor[d], 1);
    srcs[pos] = s;
}

// ---------------- softmax + aggregation: one block per dst node ----------------
__global__ __launch_bounds__(256) void agg_kernel(const unsigned short* __restrict__ Wh,
                                                  const float* __restrict__ el,
                                                  const float* __restrict__ er,
                                                  const int* __restrict__ offset,
                                                  const int* __restrict__ srcs,
                                                  float* __restrict__ out) {
    __shared__ float er_sh[HEADS];
    __shared__ float denom_sh[HEADS];
    int n = blockIdx.x;
    int t = threadIdx.x;
    int h = t >> 5;             // 32 threads per head
    if (t < HEADS) er_sh[t] = er[n * HEADS + t];
    __syncthreads();
    int start = offset[n], end = offset[n + 1];
    float ern = er_sh[h];

    // pass 1: denominator per head (exp-max skip is exact: softmax is shift-invariant,
    // scores are O(+-10) so fp32 exp cannot overflow; self-loop => segment non-empty)
    int l32 = t & 31;
    float dsum = 0.f;
    for (int j = start + l32; j < end; j += 32) {
        int s = srcs[j];
        float sc = el[s * HEADS + h] + ern;
        sc = sc >= 0.f ? sc : NEG_SLOPE * sc;
        dsum += __expf(sc);
    }
#pragma unroll
    for (int m = 16; m >= 1; m >>= 1) dsum += __shfl_xor(dsum, m, 32);
    if (l32 == 0) denom_sh[h] = dsum;
    __syncthreads();

    float inv_den = 1.0f / (denom_sh[h] + 1e-16f);
    float acc = 0.f;
    for (int j = start; j < end; ++j) {
        int s = srcs[j];
        float sc = el[s * HEADS + h] + ern;
        sc = sc >= 0.f ? sc : NEG_SLOPE * sc;
        float alpha = __expf(sc) * inv_den;
        acc = fmaf(alpha, bf2f(Wh[(size_t)s * HC + t]), acc);
    }
    out[(size_t)n * HC + t] = acc;
}

// Diagnostic: ws too small -> fill out with 1e6 so absmax ~1e6 identifies the cause.
__global__ void sentinel_kernel(float* __restrict__ out, int n) {
    int i = blockIdx.x * blockDim.x + threadIdx.x;
    if (i < n) out[i] = 1.0e6f;
}

extern "C" void kernel_launch(void* const* d_in, const int* in_sizes, int n_in,
                              void* d_out, int out_size, void* d_ws, size_t ws_size,
                              hipStream_t stream) {
    const float* x       = (const float*)d_in[0];
    const int*   ei      = (const int*)d_in[1];    // [2, E] int32
    const float* W       = (const float*)d_in[2];
    const float* a_left  = (const float*)d_in[3];
    const float* a_right = (const float*)d_in[4];
    float* out = (float*)d_out;

    const int* src = ei;
    const int* dst = ei + N_EDGES;

    char* ws = (char*)d_ws;
    size_t off = 0;
    auto alloc = [&](size_t bytes) -> void* {
        void* p = ws + off;
        off += (bytes + 255) & ~(size_t)255;
        return p;
    };
    unsigned short* Wh = (unsigned short*)alloc((size_t)N_NODES * HC * sizeof(unsigned short)); // 25.6 MB
    float* el     = (float*)alloc((size_t)N_NODES * HEADS * sizeof(float));  // 1.6 MB
    float* er     = (float*)alloc((size_t)N_NODES * HEADS * sizeof(float));  // 1.6 MB
    int*   count  = (int*)alloc((size_t)N_NODES * sizeof(int));
    int*   offset = (int*)alloc((size_t)(N_NODES + 1) * sizeof(int));
    int*   cursor = (int*)alloc((size_t)N_NODES * sizeof(int));
    int*   srcs   = (int*)alloc((size_t)E_TOT * sizeof(int));
    // total ~32.8 MB

    if (off > ws_size) {  // workspace too small: never touch ws, emit sentinel
        sentinel_kernel<<<(out_size + 255) / 256, 256, 0, stream>>>(out, out_size);
        return;
    }

    dim3 ggrid((N_NODES + 63) / 64, HC / 64);
    gemm_kernel<<<ggrid, 256, 0, stream>>>(x, W, a_left, a_right, Wh, el, er);

    zero_kernel<<<(N_NODES + 255) / 256, 256, 0, stream>>>(count, N_NODES);
    int eblocks = (E_TOT + 255) / 256;
    hist_kernel<<<eblocks, 256, 0, stream>>>(src, dst, count);
    scan_kernel<<<1, 256, 0, stream>>>(count, offset, cursor);
    scatter_kernel<<<eblocks, 256, 0, stream>>>(src, dst, cursor, srcs);

    agg_kernel<<<N_NODES, 256, 0, stream>>>(Wh, el, er, offset, srcs, out);
}

// Round 4
// 367.029 us; speedup vs baseline: 1.7087x; 1.7087x over previous
//
#include <hip/hip_runtime.h>
#include <hip/hip_bf16.h>

#define N_NODES 50000
#define N_EDGES 800000
#define IN_CH 256
#define HEADS 8
#define OUT_CH 32
#define HC 256            // HEADS*OUT_CH
#define E_TOT (N_EDGES + N_NODES)
#define NEG_SLOPE 0.2f

typedef short s16x8 __attribute__((ext_vector_type(8)));
typedef float f32x4 __attribute__((ext_vector_type(4)));

// ---- bf16 helpers via raw bits (RNE) ----
__device__ __forceinline__ unsigned short f2bf(float f) {
    unsigned int u = __float_as_uint(f);
    unsigned int r = (u + 0x7FFFu + ((u >> 16) & 1u)) >> 16;
    return (unsigned short)r;
}
__device__ __forceinline__ float bf2f(unsigned short b) {
    return __uint_as_float(((unsigned int)b) << 16);
}

// Swizzled byte offset in a [rows][32] bf16 LDS tile (row stride 64 B).
// XOR of byte-bit4 with row&7 makes ds_read_b128 column reads conflict-free (G4).
__device__ __forceinline__ int tbyte(int r, int k2) { return (r * 64 + k2) ^ ((r & 7) << 4); }

// ---------------- GEMM: Wh(bf16) = x @ W^T via MFMA, fused el/er epilogue ----
// M=50000, N=256(all cols), K=256. Block: 64 rows x 256 cols, 512 thr = 8 waves.
// Wave (wr=w&3, wc=w>>2): rows wr*16..+15, cols wc*128..+127 (8 n-tiles of 16).
__global__ __launch_bounds__(512) void gemm_kernel(const float* __restrict__ x,
                                                   const float* __restrict__ W,
                                                   const float* __restrict__ a_left,
                                                   const float* __restrict__ a_right,
                                                   unsigned short* __restrict__ Wh,
                                                   float* __restrict__ el,
                                                   float* __restrict__ er) {
    __shared__ unsigned short As[64 * 32];    // 4 KB
    __shared__ unsigned short Bs[256 * 32];   // 16 KB
    char* Asb = (char*)As;
    char* Bsb = (char*)Bs;
    const int m0 = blockIdx.x * 64;
    const int t  = threadIdx.x;
    const int l  = t & 63;
    const int wv = t >> 6;
    const int wr = wv & 3;        // 16-row group
    const int wc = wv >> 1 >> 1;  // 0..1: 128-col half
    const int c16  = l & 15;
    const int rgrp = l >> 4;      // 0..3

    f32x4 acc[8];
#pragma unroll
    for (int i = 0; i < 8; ++i) acc[i] = (f32x4){0.f, 0.f, 0.f, 0.f};

    for (int k0 = 0; k0 < IN_CH; k0 += 32) {
        {   // stage A tile: 64 rows x 32 k, 4 elems/thread
            int r = t >> 3, kq = (t & 7) << 2;
            float4 v = make_float4(0.f, 0.f, 0.f, 0.f);
            if (m0 + r < N_NODES) v = *(const float4*)&x[(size_t)(m0 + r) * IN_CH + k0 + kq];
            ushort4 o; o.x = f2bf(v.x); o.y = f2bf(v.y); o.z = f2bf(v.z); o.w = f2bf(v.w);
            *(ushort4*)(Asb + tbyte(r, kq * 2)) = o;
        }
        {   // stage B tile: 256 rows x 32 k, 16 elems/thread
            int r = t >> 1, kq = (t & 1) << 4;
            const float* wp = &W[(size_t)r * IN_CH + k0 + kq];
            float4 v0 = *(const float4*)(wp + 0);
            float4 v1 = *(const float4*)(wp + 4);
            float4 v2 = *(const float4*)(wp + 8);
            float4 v3 = *(const float4*)(wp + 12);
            ushort4 o0, o1, o2, o3;
            o0.x = f2bf(v0.x); o0.y = f2bf(v0.y); o0.z = f2bf(v0.z); o0.w = f2bf(v0.w);
            o1.x = f2bf(v1.x); o1.y = f2bf(v1.y); o1.z = f2bf(v1.z); o1.w = f2bf(v1.w);
            o2.x = f2bf(v2.x); o2.y = f2bf(v2.y); o2.z = f2bf(v2.z); o2.w = f2bf(v2.w);
            o3.x = f2bf(v3.x); o3.y = f2bf(v3.y); o3.z = f2bf(v3.z); o3.w = f2bf(v3.w);
            int b0 = kq * 2;
            *(ushort4*)(Bsb + tbyte(r, b0 + 0))  = o0;
            *(ushort4*)(Bsb + tbyte(r, b0 + 8))  = o1;
            *(ushort4*)(Bsb + tbyte(r, b0 + 16)) = o2;
            *(ushort4*)(Bsb + tbyte(r, b0 + 24)) = o3;
        }
        __syncthreads();
        // A-frag: lane holds A[row=c16][k=rgrp*8+j], 8 contiguous bf16 = 16 B
        s16x8 af = *(const s16x8*)(Asb + tbyte(wr * 16 + c16, rgrp * 16));
#pragma unroll
        for (int nt = 0; nt < 8; ++nt) {
            s16x8 bf = *(const s16x8*)(Bsb + tbyte(wc * 128 + nt * 16 + c16, rgrp * 16));
            acc[nt] = __builtin_amdgcn_mfma_f32_16x16x32_bf16(af, bf, acc[nt], 0, 0, 0);
        }
        __syncthreads();
    }

    // Epilogue. C/D layout (m89): col = lane&15, row = (lane>>4)*4 + reg.
    // el/er from fp32 accumulators (head = 2 adjacent n-tiles), then bf16 Wh store.
#pragma unroll
    for (int hp = 0; hp < 4; ++hp) {
        int hg  = wc * 4 + hp;           // global head
        int nt0 = hp * 2;
        float al0 = a_left [hg * OUT_CH + c16];
        float al1 = a_left [hg * OUT_CH + 16 + c16];
        float ar0 = a_right[hg * OUT_CH + c16];
        float ar1 = a_right[hg * OUT_CH + 16 + c16];
#pragma unroll
        for (int rg = 0; rg < 4; ++rg) {
            float pl = acc[nt0][rg] * al0 + acc[nt0 + 1][rg] * al1;
            float pr = acc[nt0][rg] * ar0 + acc[nt0 + 1][rg] * ar1;
#pragma unroll
            for (int m = 1; m < 16; m <<= 1) {
                pl += __shfl_xor(pl, m, 16);
                pr += __shfl_xor(pr, m, 16);
            }
            int row = m0 + wr * 16 + rgrp * 4 + rg;
            if (c16 == 0 && row < N_NODES) {
                el[row * HEADS + hg] = pl;
                er[row * HEADS + hg] = pr;
            }
        }
    }
#pragma unroll
    for (int nt = 0; nt < 8; ++nt) {
#pragma unroll
        for (int rg = 0; rg < 4; ++rg) {
            int row = m0 + wr * 16 + rgrp * 4 + rg;
            if (row < N_NODES)
                Wh[(size_t)row * HC + wc * 128 + nt * 16 + c16] = f2bf(acc[nt][rg]);
        }
    }
}

// ---------------- CSR build ----------------
__global__ void zero_kernel(int* __restrict__ p, int n) {
    int i = blockIdx.x * blockDim.x + threadIdx.x;
    if (i < n) p[i] = 0;
}

__global__ void hist_kernel(const int* __restrict__ src, const int* __restrict__ dst,
                            int* __restrict__ count) {
    int e = blockIdx.x * blockDim.x + threadIdx.x;
    if (e >= E_TOT) return;
    int s, d;
    if (e < N_EDGES) { s = src[e]; d = dst[e]; } else { s = d = e - N_EDGES; }
    if ((unsigned)s >= N_NODES || (unsigned)d >= N_NODES) return;  // fault-proofing
    atomicAdd(&count[d], 1);
}

__global__ __launch_bounds__(1024) void scan_kernel(const int* __restrict__ count,
                                                    int* __restrict__ offset,
                                                    int* __restrict__ cursor) {
    __shared__ int wtot[16];
    __shared__ int wbase[16];
    __shared__ int running_s;
    int t = threadIdx.x, lane = t & 63, wid = t >> 6;
    if (t == 0) running_s = 0;
    __syncthreads();
    for (int base = 0; base < N_NODES; base += 1024) {
        int idx = base + t;
        int v = (idx < N_NODES) ? count[idx] : 0;
        int s = v;
#pragma unroll
        for (int off = 1; off < 64; off <<= 1) {
            int u = __shfl_up(s, off, 64);
            if (lane >= off) s += u;
        }
        if (lane == 63) wtot[wid] = s;
        __syncthreads();
        if (t == 0) {
            int b = running_s;
            for (int w = 0; w < 16; ++w) { wbase[w] = b; b += wtot[w]; }
            running_s = b;
        }
        __syncthreads();
        int excl = s - v + wbase[wid];
        if (idx < N_NODES) { offset[idx] = excl; cursor[idx] = excl; }
        __syncthreads();
    }
    if (t == 0) offset[N_NODES] = running_s;
}

__global__ void scatter_kernel(const int* __restrict__ src, const int* __restrict__ dst,
                               int* __restrict__ cursor, int* __restrict__ srcs) {
    int e = blockIdx.x * blockDim.x + threadIdx.x;
    if (e >= E_TOT) return;
    int s, d;
    if (e < N_EDGES) { s = src[e]; d = dst[e]; } else { s = d = e - N_EDGES; }
    if ((unsigned)s >= N_NODES || (unsigned)d >= N_NODES) return;
    int pos = atomicAdd(&cursor[d], 1);
    srcs[pos] = s;
}

// ---------------- softmax + aggregation: one block per dst node, single pass ----
// out = (sum_e exp(sc_e) * Wh[src_e]) / (sum_e exp(sc_e) + eps)  -- shift-invariant,
// identical to reference softmax (scores ~N(0,1.4), exp cannot overflow; self-loop
// guarantees non-empty segment). Unroll-4 puts 4 Wh gathers in flight.
__global__ __launch_bounds__(256) void agg_kernel(const unsigned short* __restrict__ Wh,
                                                  const float* __restrict__ el,
                                                  const float* __restrict__ er,
                                                  const int* __restrict__ offset,
                                                  const int* __restrict__ srcs,
                                                  float* __restrict__ out) {
    int n = blockIdx.x;
    int t = threadIdx.x;
    int h = t >> 5;
    float ern = er[n * HEADS + h];
    int start = offset[n], end = offset[n + 1];
    float acc = 0.f, den = 0.f;
    int j = start;
    for (; j + 4 <= end; j += 4) {
        int s0 = srcs[j + 0], s1 = srcs[j + 1], s2 = srcs[j + 2], s3 = srcs[j + 3];
        float w0 = bf2f(Wh[(size_t)s0 * HC + t]);
        float w1 = bf2f(Wh[(size_t)s1 * HC + t]);
        float w2 = bf2f(Wh[(size_t)s2 * HC + t]);
        float w3 = bf2f(Wh[(size_t)s3 * HC + t]);
        float sc0 = el[s0 * HEADS + h] + ern;
        float sc1 = el[s1 * HEADS + h] + ern;
        float sc2 = el[s2 * HEADS + h] + ern;
        float sc3 = el[s3 * HEADS + h] + ern;
        sc0 = fmaxf(sc0, NEG_SLOPE * sc0);   // leaky-relu == max(x, 0.2x)
        sc1 = fmaxf(sc1, NEG_SLOPE * sc1);
        sc2 = fmaxf(sc2, NEG_SLOPE * sc2);
        sc3 = fmaxf(sc3, NEG_SLOPE * sc3);
        float e0 = __expf(sc0), e1 = __expf(sc1), e2 = __expf(sc2), e3 = __expf(sc3);
        acc = fmaf(e0, w0, acc);
        acc = fmaf(e1, w1, acc);
        acc = fmaf(e2, w2, acc);
        acc = fmaf(e3, w3, acc);
        den += (e0 + e1) + (e2 + e3);
    }
    for (; j < end; ++j) {
        int s = srcs[j];
        float sc = el[s * HEADS + h] + ern;
        sc = fmaxf(sc, NEG_SLOPE * sc);
        float e = __expf(sc);
        acc = fmaf(e, bf2f(Wh[(size_t)s * HC + t]), acc);
        den += e;
    }
    out[(size_t)n * HC + t] = acc / (den + 1e-16f);
}

// Diagnostic: ws too small -> absmax ~1e6 identifies the cause.
__global__ void sentinel_kernel(float* __restrict__ out, int n) {
    int i = blockIdx.x * blockDim.x + threadIdx.x;
    if (i < n) out[i] = 1.0e6f;
}

extern "C" void kernel_launch(void* const* d_in, const int* in_sizes, int n_in,
                              void* d_out, int out_size, void* d_ws, size_t ws_size,
                              hipStream_t stream) {
    const float* x       = (const float*)d_in[0];
    const int*   ei      = (const int*)d_in[1];    // [2, E] int32
    const float* W       = (const float*)d_in[2];
    const float* a_left  = (const float*)d_in[3];
    const float* a_right = (const float*)d_in[4];
    float* out = (float*)d_out;

    const int* src = ei;
    const int* dst = ei + N_EDGES;

    char* ws = (char*)d_ws;
    size_t off = 0;
    auto alloc = [&](size_t bytes) -> void* {
        void* p = ws + off;
        off += (bytes + 255) & ~(size_t)255;
        return p;
    };
    unsigned short* Wh = (unsigned short*)alloc((size_t)N_NODES * HC * sizeof(unsigned short)); // 25.6 MB
    float* el     = (float*)alloc((size_t)N_NODES * HEADS * sizeof(float));
    float* er     = (float*)alloc((size_t)N_NODES * HEADS * sizeof(float));
    int*   count  = (int*)alloc((size_t)N_NODES * sizeof(int));
    int*   offset = (int*)alloc((size_t)(N_NODES + 1) * sizeof(int));
    int*   cursor = (int*)alloc((size_t)N_NODES * sizeof(int));
    int*   srcs   = (int*)alloc((size_t)E_TOT * sizeof(int));
    // total ~32.8 MB

    if (off > ws_size) {
        sentinel_kernel<<<(out_size + 255) / 256, 256, 0, stream>>>(out, out_size);
        return;
    }

    gemm_kernel<<<(N_NODES + 63) / 64, 512, 0, stream>>>(x, W, a_left, a_right, Wh, el, er);

    zero_kernel<<<(N_NODES + 255) / 256, 256, 0, stream>>>(count, N_NODES);
    int eblocks = (E_TOT + 255) / 256;
    hist_kernel<<<eblocks, 256, 0, stream>>>(src, dst, count);
    scan_kernel<<<1, 1024, 0, stream>>>(count, offset, cursor);
    scatter_kernel<<<eblocks, 256, 0, stream>>>(src, dst, cursor, srcs);

    agg_kernel<<<N_NODES, 256, 0, stream>>>(Wh, el, er, offset, srcs, out);
}